// Round 4
// baseline (1071.632 us; speedup 1.0000x reference)
//
#include <hip/hip_runtime.h>

using u16 = unsigned short;
using u32 = unsigned int;

typedef __attribute__((ext_vector_type(8))) short bf16x8;
typedef __attribute__((ext_vector_type(4))) float f32x4;

#define NTOK 16384
#define PS ((size_t)16384 * 64)   // logits plane stride

// ---------------- workspace layout (bytes) ----------------
constexpr size_t OFF_FLAG    = 0;
constexpr size_t OFF_FCNT    = 256;
constexpr size_t OFF_M       = 512;        // 1024 f64
constexpr size_t OFF_B1P64   = 8704;       // 512 f64
constexpr size_t OFF_B1P32   = 12800;      // 512 f32
constexpr size_t OFF_BIHF    = 14848;      // 3072 f32
constexpr size_t OFF_BHHF    = 27136;      // 3072 f32
constexpr size_t OFF_BVF     = 39424;      // 1024 f32
constexpr size_t OFF_BOF     = 43520;      // 1024 f32
constexpr size_t OFF_LISTCNT = 47616;      // 256 int
constexpr size_t OFF_WSUM    = 48640;      // 256 f32
constexpr size_t OFF_FLAGS   = 49664;      // 16384 int
constexpr size_t OFF_HSHI    = 115200;     // 64*1024 u16
constexpr size_t OFF_HSLO    = 246272;
constexpr size_t OFF_HSF     = 377344;     // 64*1024 f32
constexpr size_t OFF_GH      = 639488;     // 64*3072 f32
constexpr size_t OFF_GIHI    = 1425920;    // 256*1024 u16
constexpr size_t OFF_GILO    = 1950208;
constexpr size_t OFF_GX      = 2474496;    // 256*3072 f32
constexpr size_t OFF_SNHI    = 5620224;    // 256*1024 u16
constexpr size_t OFF_SNLO    = 6144512;
constexpr size_t OFF_SVHI    = 6668800;
constexpr size_t OFF_SVLO    = 7193088;
constexpr size_t OFF_SVO     = 7717376;    // 256*1024 f32
constexpr size_t OFF_IDX     = 8765952;    // 16384*8 int
constexpr size_t OFF_WGT     = 9290240;    // 16384*8 f32
constexpr size_t OFF_LOGITS  = 9814528;    // 4 planes x 16384*64 f32 = 16 MB
constexpr size_t OFF_ETOK    = 9814528;    // alias: logits dead after k_topk
constexpr size_t OFF_EW      = 14008832;
constexpr size_t OFF_W1HI    = 26591744;   // 512*2048 u16
constexpr size_t OFF_W1LO    = 28688896;
constexpr size_t OFF_W2HI    = 30786048;   // 64*512 u16
constexpr size_t OFF_W2LO    = 30851584;
constexpr size_t OFF_XHI     = 30917120;   // 16384*1024 u16 = 32 MB
// aliases inside XHI (x splits dead after router; k_accum/k_repair read raw x):
constexpr size_t OFF_WIHHI   = 30917120;   // 3072*1024 u16
constexpr size_t OFF_WIHLO   = 37208576;
constexpr size_t OFF_WHHHI   = 43500032;
constexpr size_t OFF_WHHLO   = 49791488;
constexpr size_t OFF_WVHI    = 56082944;   // 1024*1024 u16
constexpr size_t OFF_WVLO    = 58180096;
constexpr size_t OFF_WOHI    = 60277248;
constexpr size_t OFF_WOLO    = 62374400;
constexpr size_t OFF_XLO     = 64471552;   // 32 MB
constexpr size_t WS_NEED     = 98025984;   // <= 101,169,920 proven available

// ---------------- helpers ----------------
__device__ __forceinline__ float bf2f(u16 u) {
  union { u32 i; float f; } c; c.i = ((u32)u) << 16; return c.f;
}
__device__ __forceinline__ u16 f2bf(float f) {  // RNE
  u32 x = __float_as_uint(f);
  x += 0x7fffu + ((x >> 16) & 1u);
  return (u16)(x >> 16);
}
__device__ __forceinline__ void splitf(float v, u16& hi, u16& lo) {
  hi = f2bf(v);
  lo = f2bf(v - bf2f(hi));
}
__device__ __forceinline__ float rdval(const void* p, int i, int f32m) {
  return f32m ? ((const float*)p)[i] : bf2f(((const u16*)p)[i]);
}
__device__ __forceinline__ void async16(const u16* g, u16* l) {
  __builtin_amdgcn_global_load_lds((const __attribute__((address_space(1))) void*)g,
                                   (__attribute__((address_space(3))) void*)l, 16, 0, 0);
}
__device__ __forceinline__ void cvt_quad(const void* src, u16* hi, u16* lo,
                                         size_t qi, int f) {
  if (f) {
    float4 v = ((const float4*)src)[qi];
    ushort4 h, l;
    splitf(v.x, h.x, l.x); splitf(v.y, h.y, l.y);
    splitf(v.z, h.z, l.z); splitf(v.w, h.w, l.w);
    ((ushort4*)hi)[qi] = h; ((ushort4*)lo)[qi] = l;
  } else {
    ((ushort4*)hi)[qi] = ((const ushort4*)src)[qi];
    ushort4 z; z.x = z.y = z.z = z.w = 0;
    ((ushort4*)lo)[qi] = z;
  }
}

// ---------------- dtype sniffer ----------------
__global__ void k_sniff(const u32* __restrict__ w1w, int* __restrict__ flag) {
  int t = threadIdx.x;
  u32 word = w1w[t * 97];
  int ef = (word >> 7) & 0xFF;
  unsigned long long m = __ballot(ef >= 128);
  if (t == 0) flag[0] = (__popcll(m) >= 8) ? 1 : 0;
}

// ---------------- conversions ----------------
__global__ __launch_bounds__(256) void k_cvt_x(const void* __restrict__ src,
    u16* __restrict__ hi, u16* __restrict__ lo, const int* __restrict__ flagp) {
  int f = *flagp;
  size_t qi = (size_t)blockIdx.x * 256 + threadIdx.x;   // 4,194,304 quads exact
  cvt_quad(src, hi, lo, qi, f);
}
__global__ __launch_bounds__(256) void k_cvt_w1w2(
    const void* __restrict__ w1, u16* __restrict__ w1hi, u16* __restrict__ w1lo,
    const void* __restrict__ w2, u16* __restrict__ w2hi, u16* __restrict__ w2lo,
    const int* __restrict__ flagp) {
  int f = *flagp;
  size_t qi = (size_t)blockIdx.x * 256 + threadIdx.x;   // 270,336 quads exact
  if (qi < 262144) cvt_quad(w1, w1hi, w1lo, qi, f);
  else             cvt_quad(w2, w2hi, w2lo, qi - 262144, f);
}
__global__ __launch_bounds__(256) void k_cvt_late(
    const void* __restrict__ wih, u16* __restrict__ wihhi, u16* __restrict__ wihlo,
    const void* __restrict__ whh, u16* __restrict__ whhhi, u16* __restrict__ whhlo,
    const void* __restrict__ wv,  u16* __restrict__ wvhi,  u16* __restrict__ wvlo,
    const void* __restrict__ wo,  u16* __restrict__ wohi,  u16* __restrict__ wolo,
    const int* __restrict__ flagp) {
  int f = *flagp;
  size_t qi = (size_t)blockIdx.x * 256 + threadIdx.x;   // 2,097,152 quads exact
  if      (qi < 786432)  cvt_quad(wih, wihhi, wihlo, qi, f);
  else if (qi < 1572864) cvt_quad(whh, whhhi, whhlo, qi - 786432, f);
  else if (qi < 1835008) cvt_quad(wv, wvhi, wvlo, qi - 1572864, f);
  else                   cvt_quad(wo, wohi, wolo, qi - 1835008, f);
}

// ---------------- generic bt-GEMM (3-pass split): C = A @ B^T ----------------
// MODE 0: outF = acc + biasF[col].  MODE 3: split-bf16 out.
template<int MODE>
__global__ __launch_bounds__(256, 2) void gemm_bt(
    const u16* __restrict__ Ahi, const u16* __restrict__ Alo,
    const u16* __restrict__ Bhi, const u16* __restrict__ Blo,
    int M, int N, int K, int ldb,
    const float* __restrict__ biasF, float* __restrict__ outF,
    u16* __restrict__ outHi, u16* __restrict__ outLo)
{
  __shared__ alignas(16) u16 At[128 * 32];
  __shared__ alignas(16) u16 Bt[128 * 32];
  const int t    = threadIdx.x;
  const int wvid = t >> 6;
  const int lane = t & 63;
  const int quad = lane >> 4;
  const int l16  = lane & 15;
  const int row0 = blockIdx.x * 128;
  const int col0 = blockIdx.y * 128;
  const int wr   = (wvid >> 1) * 64;
  const int wc   = (wvid & 1) * 64;

  const int ra  = t >> 2;
  const int kqe = (t & 3) * 8;
  int r_a0 = row0 + ra;      if (r_a0 > M - 1) r_a0 = M - 1;
  int r_a1 = row0 + ra + 64; if (r_a1 > M - 1) r_a1 = M - 1;
  int r_b0 = col0 + ra;      if (r_b0 > N - 1) r_b0 = N - 1;
  int r_b1 = col0 + ra + 64; if (r_b1 > N - 1) r_b1 = N - 1;

  f32x4 acc[4][4] = {};

  for (int p = 0; p < 3; ++p) {
    const u16* Ap = (p == 1) ? Alo : Ahi;
    const u16* Bp = (p == 2) ? Blo : Bhi;
    const u16* gA0 = Ap + (size_t)r_a0 * K + kqe;
    const u16* gA1 = Ap + (size_t)r_a1 * K + kqe;
    const u16* gB0 = Bp + (size_t)r_b0 * ldb + kqe;
    const u16* gB1 = Bp + (size_t)r_b1 * ldb + kqe;
    for (int k0 = 0; k0 < K; k0 += 32) {
      async16(gA0 + k0, &At[(wvid * 64) * 8]);
      async16(gA1 + k0, &At[(wvid * 64 + 256) * 8]);
      async16(gB0 + k0, &Bt[(wvid * 64) * 8]);
      async16(gB1 + k0, &Bt[(wvid * 64 + 256) * 8]);
      asm volatile("s_waitcnt vmcnt(0)" ::: "memory");
      __syncthreads();
      bf16x8 af[4], bfr[4];
      #pragma unroll
      for (int mt = 0; mt < 4; ++mt)
        af[mt] = *(const bf16x8*)&At[(wr + mt * 16 + l16) * 32 + quad * 8];
      #pragma unroll
      for (int nt = 0; nt < 4; ++nt)
        bfr[nt] = *(const bf16x8*)&Bt[(wc + nt * 16 + l16) * 32 + quad * 8];
      #pragma unroll
      for (int mt = 0; mt < 4; ++mt)
        #pragma unroll
        for (int nt = 0; nt < 4; ++nt)
          acc[mt][nt] = __builtin_amdgcn_mfma_f32_16x16x32_bf16(
              af[mt], bfr[nt], acc[mt][nt], 0, 0, 0);
      __syncthreads();
    }
  }

  #pragma unroll
  for (int mt = 0; mt < 4; ++mt) {
    #pragma unroll
    for (int nt = 0; nt < 4; ++nt) {
      const int col = col0 + wc + nt * 16 + l16;
      if (col >= N) continue;
      #pragma unroll
      for (int r2 = 0; r2 < 4; ++r2) {
        const int row = row0 + wr + mt * 16 + quad * 4 + r2;
        if (row >= M) continue;
        float v = acc[mt][nt][r2] + biasF[col];
        size_t idx = (size_t)row * N + col;
        if constexpr (MODE == 0) {
          outF[idx] = v;
        } else {
          u16 hi, lo; splitf(v, hi, lo);
          outHi[idx] = hi; outLo[idx] = lo;
        }
      }
    }
  }
}

// ---------------- router GEMM fused with logits ----------------
// h_tile = gelu(x@w1a^T + b1') for rows [row0,row0+128), cols [col0,col0+128)
// then logitsP[by] [rows,64] = h_tile @ w2[:, col0:col0+128]^T  (3 split passes)
__global__ __launch_bounds__(256, 2) void gemm_router_fused(
    const u16* __restrict__ Ahi, const u16* __restrict__ Alo,   // x splits, ld 1024
    const u16* __restrict__ Bhi, const u16* __restrict__ Blo,   // w1 splits, ld 2048
    const u16* __restrict__ W2hig, const u16* __restrict__ W2log, // ld 512
    const float* __restrict__ b1p32, float* __restrict__ logitsP)
{
  __shared__ alignas(16) u16 buf[25600];   // 51,200 B -> fits 2 blocks/CU
  u16* Athi = buf;            // 4096 u16
  u16* Atlo = buf + 4096;
  u16* Bthi = buf + 8192;
  u16* Btlo = buf + 12288;
  u16* Ht   = buf;            // 128 x 136 (padded) = 17408 u16, aliases A/B tiles
  u16* W2t  = buf + 17408;    // 64 x 128 = 8192 u16

  const int t = threadIdx.x, wvid = t >> 6, lane = t & 63;
  const int quad = lane >> 4, l16 = lane & 15;
  const int row0 = blockIdx.x * 128;
  const int col0 = blockIdx.y * 128;
  const int wr = (wvid >> 1) * 64, wc = (wvid & 1) * 64;
  const int ra = t >> 2, kqe = (t & 3) * 8;

  const u16* gAh0 = Ahi + (size_t)(row0 + ra) * 1024 + kqe;
  const u16* gAh1 = Ahi + (size_t)(row0 + ra + 64) * 1024 + kqe;
  const u16* gAl0 = Alo + (size_t)(row0 + ra) * 1024 + kqe;
  const u16* gAl1 = Alo + (size_t)(row0 + ra + 64) * 1024 + kqe;
  const u16* gBh0 = Bhi + (size_t)(col0 + ra) * 2048 + kqe;
  const u16* gBh1 = Bhi + (size_t)(col0 + ra + 64) * 2048 + kqe;
  const u16* gBl0 = Blo + (size_t)(col0 + ra) * 2048 + kqe;
  const u16* gBl1 = Blo + (size_t)(col0 + ra + 64) * 2048 + kqe;

  f32x4 acc[4][4] = {};
  for (int k0 = 0; k0 < 1024; k0 += 32) {
    async16(gAh0 + k0, &Athi[(wvid * 64) * 8]);
    async16(gAh1 + k0, &Athi[(wvid * 64 + 256) * 8]);
    async16(gAl0 + k0, &Atlo[(wvid * 64) * 8]);
    async16(gAl1 + k0, &Atlo[(wvid * 64 + 256) * 8]);
    async16(gBh0 + k0, &Bthi[(wvid * 64) * 8]);
    async16(gBh1 + k0, &Bthi[(wvid * 64 + 256) * 8]);
    async16(gBl0 + k0, &Btlo[(wvid * 64) * 8]);
    async16(gBl1 + k0, &Btlo[(wvid * 64 + 256) * 8]);
    asm volatile("s_waitcnt vmcnt(0)" ::: "memory");
    __syncthreads();
    bf16x8 ah[4], al[4], bh[4], bl[4];
    #pragma unroll
    for (int mt = 0; mt < 4; ++mt) {
      ah[mt] = *(const bf16x8*)&Athi[(wr + mt * 16 + l16) * 32 + quad * 8];
      al[mt] = *(const bf16x8*)&Atlo[(wr + mt * 16 + l16) * 32 + quad * 8];
    }
    #pragma unroll
    for (int nt = 0; nt < 4; ++nt) {
      bh[nt] = *(const bf16x8*)&Bthi[(wc + nt * 16 + l16) * 32 + quad * 8];
      bl[nt] = *(const bf16x8*)&Btlo[(wc + nt * 16 + l16) * 32 + quad * 8];
    }
    #pragma unroll
    for (int mt = 0; mt < 4; ++mt)
      #pragma unroll
      for (int nt = 0; nt < 4; ++nt) {
        acc[mt][nt] = __builtin_amdgcn_mfma_f32_16x16x32_bf16(
            ah[mt], bh[nt], acc[mt][nt], 0, 0, 0);
        acc[mt][nt] = __builtin_amdgcn_mfma_f32_16x16x32_bf16(
            al[mt], bh[nt], acc[mt][nt], 0, 0, 0);
        acc[mt][nt] = __builtin_amdgcn_mfma_f32_16x16x32_bf16(
            ah[mt], bl[nt], acc[mt][nt], 0, 0, 0);
      }
    __syncthreads();
  }

  // ---- epilogue: gelu, then fused logits partial GEMM ----
  float varr[4][4][4];
  #pragma unroll
  for (int mt = 0; mt < 4; ++mt)
    #pragma unroll
    for (int nt = 0; nt < 4; ++nt) {
      const int col = wc + nt * 16 + l16;
      #pragma unroll
      for (int r2 = 0; r2 < 4; ++r2) {
        float v = acc[mt][nt][r2] + b1p32[col0 + col];
        varr[mt][nt][r2] = 0.5f * v * (1.0f + erff(v * 0.70710678118654752f));
      }
    }

  const int wr2 = (wvid >> 1) * 64, wc2 = (wvid & 1) * 32;
  f32x4 accP[4][2] = {};

  auto writeHt = [&](bool hiPlane) {
    #pragma unroll
    for (int mt = 0; mt < 4; ++mt)
      #pragma unroll
      for (int nt = 0; nt < 4; ++nt) {
        const int col = wc + nt * 16 + l16;
        #pragma unroll
        for (int r2 = 0; r2 < 4; ++r2) {
          const int row = wr + mt * 16 + quad * 4 + r2;
          u16 hi, lo; splitf(varr[mt][nt][r2], hi, lo);
          Ht[row * 136 + col] = hiPlane ? hi : lo;
        }
      }
  };
  auto stageW2 = [&](const u16* W2g) {
    const int s = t >> 2;
    #pragma unroll
    for (int j = 0; j < 4; ++j) {
      const int k = (t & 3) * 32 + j * 8;
      *(bf16x8*)&W2t[s * 128 + k] =
          *(const bf16x8*)(W2g + (size_t)s * 512 + col0 + k);
    }
  };
  auto mmP = [&]() {
    #pragma unroll
    for (int ks = 0; ks < 4; ++ks) {
      bf16x8 am[4], bm[2];
      #pragma unroll
      for (int mt = 0; mt < 4; ++mt)
        am[mt] = *(const bf16x8*)&Ht[(wr2 + mt * 16 + l16) * 136 + ks * 32 + quad * 8];
      #pragma unroll
      for (int np = 0; np < 2; ++np)
        bm[np] = *(const bf16x8*)&W2t[(wc2 + np * 16 + l16) * 128 + ks * 32 + quad * 8];
      #pragma unroll
      for (int mt = 0; mt < 4; ++mt)
        #pragma unroll
        for (int np = 0; np < 2; ++np)
          accP[mt][np] = __builtin_amdgcn_mfma_f32_16x16x32_bf16(
              am[mt], bm[np], accP[mt][np], 0, 0, 0);
    }
  };

  writeHt(true); stageW2(W2hig);     // safe: all A/B-tile reads done pre-barrier
  __syncthreads();
  mmP();                              // Hhi * W2hi
  __syncthreads();
  writeHt(false);                     // Ht <- lo plane (W2t still hi)
  __syncthreads();
  mmP();                              // Hlo * W2hi
  __syncthreads();
  writeHt(true); stageW2(W2log);
  __syncthreads();
  mmP();                              // Hhi * W2lo

  float* lp = logitsP + (size_t)blockIdx.y * PS;
  #pragma unroll
  for (int mt = 0; mt < 4; ++mt)
    #pragma unroll
    for (int np = 0; np < 2; ++np)
      #pragma unroll
      for (int r2 = 0; r2 < 4; ++r2) {
        const int row = wr2 + mt * 16 + quad * 4 + r2;
        const int s   = wc2 + np * 16 + l16;
        lp[(size_t)(row0 + row) * 64 + s] = accP[mt][np][r2];
      }
}

// ---------------- init: counters, slot_mean f64, hs split, bias cvt ----------
__global__ __launch_bounds__(256) void k_init(const void* __restrict__ sli,
    const void* __restrict__ slsc, const int* __restrict__ flagp,
    const void* __restrict__ bih, const void* __restrict__ bhh,
    const void* __restrict__ bv, const void* __restrict__ bo,
    double* __restrict__ m64, int* __restrict__ fcnt,
    int* __restrict__ listcnt, float* __restrict__ wsum,
    u16* __restrict__ hshi, u16* __restrict__ hslo, float* __restrict__ hsf,
    float* __restrict__ bihf, float* __restrict__ bhhf,
    float* __restrict__ bvf, float* __restrict__ bof)
{
  int f = *flagp;
  int gid = blockIdx.x * 256 + threadIdx.x;   // 16384 threads
  if (gid == 0) fcnt[0] = 0;
  if (gid < 256) { listcnt[gid] = 0; wsum[gid] = 0.f; }
  if (gid < 1024) {
    double s = 0.0;
    for (int j = 0; j < 64; ++j)
      s += (double)rdval(sli, j * 1024 + gid, f) * (double)rdval(slsc, j, f);
    m64[gid] = s * (1.0 / 64.0);
    bvf[gid] = rdval(bv, gid, f);
    bof[gid] = rdval(bo, gid, f);
  }
  if (gid < 3072) { bihf[gid] = rdval(bih, gid, f); bhhf[gid] = rdval(bhh, gid, f); }
  for (int i = gid; i < 64 * 1024; i += 16384) {
    int s = i >> 10;
    float v = rdval(sli, i, f) * rdval(slsc, s, f);
    splitf(v, hshi[i], hslo[i]);
    hsf[i] = v;
  }
}

// b1' = b1 + w1[:,1024:2048] @ slot_mean (f64)
__global__ __launch_bounds__(256) void k_b1p(const void* __restrict__ w1,
    const void* __restrict__ b1, const int* __restrict__ flagp,
    const double* __restrict__ m64, double* __restrict__ b1p64,
    float* __restrict__ b1p32)
{
  int f = *flagp;
  int h = blockIdx.x * 256 + threadIdx.x;
  if (h >= 512) return;
  double a = (double)rdval(b1, h, f);
  if (f) {
    const float* wr = (const float*)w1 + (size_t)h * 2048 + 1024;
    for (int d = 0; d < 1024; ++d) a += (double)wr[d] * m64[d];
  } else {
    const u16* wr = (const u16*)w1 + (size_t)h * 2048 + 1024;
    for (int d = 0; d < 1024; ++d) a += (double)bf2f(wr[d]) * m64[d];
  }
  b1p64[h] = a;
  b1p32[h] = (float)a;
}

// ---------------- top-k per token (wave = token) ----------------
__global__ __launch_bounds__(256) void k_topk(const float* __restrict__ logits,
    const void* __restrict__ b2, const void* __restrict__ tau,
    const int* __restrict__ flagp, int* __restrict__ idxb, float* __restrict__ wgtb,
    int* __restrict__ fcnt, int* __restrict__ flags)
{
  const int f32m = *flagp;
  const int n    = blockIdx.x * 4 + (threadIdx.x >> 6);
  const int lane = threadIdx.x & 63;
  const size_t o = (size_t)n * 64 + lane;
  float cur = logits[o] + logits[PS + o] + logits[2 * PS + o] + logits[3 * PS + o]
            + rdval(b2, lane, f32m);
  float tv[8]; int ti[8]; float v9 = 0.f;
  #pragma unroll
  for (int it = 0; it < 9; ++it) {
    float v = cur; int i = lane;
    #pragma unroll
    for (int off = 32; off; off >>= 1) {   // xor-butterfly argmax, tie -> min idx
      float ov = __shfl_xor(v, off);
      int   oi = __shfl_xor(i, off);
      if (ov > v || (ov == v && oi < i)) { v = ov; i = oi; }
    }
    if (it < 8) { tv[it] = v; ti[it] = i; if (lane == i) cur = -__builtin_inff(); }
    else v9 = v;
  }
  float itau = 1.0f / (fabsf(rdval(tau, 0, f32m)) + 0.1f);
  float e[8], z = 0.f;
  #pragma unroll
  for (int k = 0; k < 8; ++k) { e[k] = expf((tv[k] - tv[0]) * itau); z += e[k]; }
  if (lane == 0) {
    float theta = f32m ? 2e-4f : 1e-4f;
    if (tv[7] - v9 < theta) { int p = atomicAdd(fcnt, 1); flags[p] = n; }
    float rz = 1.0f / z;
    #pragma unroll
    for (int k = 0; k < 8; ++k) {
      idxb[n * 8 + k] = ti[k];
      wgtb[n * 8 + k] = e[k] * rz;
    }
  }
}

// ---------------- f64 re-route of flagged tokens (raw inputs) ----------------
__global__ __launch_bounds__(256) void k_repair(const void* __restrict__ x,
    const void* __restrict__ w1, const void* __restrict__ w2,
    const void* __restrict__ b2, const void* __restrict__ tau,
    const int* __restrict__ flagp, const double* __restrict__ b1p64,
    const int* __restrict__ fcnt, const int* __restrict__ flags,
    int* __restrict__ idxb, float* __restrict__ wgtb)
{
  __shared__ double hsm[512];
  __shared__ double lg[64];
  const int f = *flagp;
  const int cnt = *fcnt;
  const int t = threadIdx.x;
  for (int q = blockIdx.x; q < cnt; q += gridDim.x) {
    const int n = flags[q];
    for (int h = t; h < 512; h += 256) {
      double a = b1p64[h];
      if (f) {
        const float* xr = (const float*)x + (size_t)n * 1024;
        const float* wr = (const float*)w1 + (size_t)h * 2048;
        for (int d = 0; d < 1024; ++d) a += (double)xr[d] * (double)wr[d];
      } else {
        const u16* xr = (const u16*)x + (size_t)n * 1024;
        const u16* wr = (const u16*)w1 + (size_t)h * 2048;
        for (int d = 0; d < 1024; ++d) a += (double)bf2f(xr[d]) * (double)bf2f(wr[d]);
      }
      hsm[h] = 0.5 * a * (1.0 + erf(a * 0.70710678118654752440));
    }
    __syncthreads();
    if (t < 64) {
      double a = (double)rdval(b2, t, f);
      if (f) {
        const float* wr = (const float*)w2 + (size_t)t * 512;
        for (int k = 0; k < 512; ++k) a += hsm[k] * (double)wr[k];
      } else {
        const u16* wr = (const u16*)w2 + (size_t)t * 512;
        for (int k = 0; k < 512; ++k) a += hsm[k] * (double)bf2f(wr[k]);
      }
      lg[t] = a;
    }
    __syncthreads();
    if (t == 0) {
      double tv = fabs((double)rdval(tau, 0, f)) + 0.1;
      double vals[8]; int ids[8];
      for (int it = 0; it < 8; ++it) {
        double best = -1e300; int bi = 0;
        for (int i = 0; i < 64; ++i)
          if (lg[i] > best) { best = lg[i]; bi = i; }
        vals[it] = best; ids[it] = bi; lg[bi] = -1e300;
      }
      double e[8], z = 0.0;
      for (int k = 0; k < 8; ++k) { e[k] = exp((vals[k] - vals[0]) / tv); z += e[k]; }
      for (int k = 0; k < 8; ++k) {
        idxb[n * 8 + k] = ids[k];
        wgtb[n * 8 + k] = (float)(e[k] / z);
      }
    }
    __syncthreads();
  }
}

// ---------------- build per-(b,slot) token lists + weight sums ---------------
__global__ __launch_bounds__(256) void k_lists(const int* __restrict__ idxb,
    const float* __restrict__ wgtb, int* __restrict__ listcnt,
    float* __restrict__ wsum, int* __restrict__ etok, float* __restrict__ ew)
{
  int n = blockIdx.x * 256 + threadIdx.x;   // 16384 tokens, one per thread
  int b = n >> 12;
  #pragma unroll
  for (int k = 0; k < 8; ++k) {
    int bs = b * 64 + idxb[n * 8 + k];
    float w = wgtb[n * 8 + k];
    int pos = atomicAdd(&listcnt[bs], 1);
    etok[bs * 4096 + pos] = n;
    ew[bs * 4096 + pos]   = w;
    atomicAdd(&wsum[bs], w);
  }
}

// ---------------- accumulate gi: grid (bs,dchunk) = 1024 blocks --------------
__global__ __launch_bounds__(256) void k_accum(const void* __restrict__ X,
    const int* __restrict__ flagp, const int* __restrict__ listcnt,
    const float* __restrict__ wsum, const int* __restrict__ etok,
    const float* __restrict__ ew, u16* __restrict__ gihi, u16* __restrict__ gilo)
{
  const int bs = blockIdx.x >> 2;
  const int d  = (blockIdx.x & 3) * 256 + threadIdx.x;
  const int cnt = listcnt[bs];
  const int seg = bs * 4096;
  float a = 0.f;
  if (*flagp) {
    const float* Xf = (const float*)X;
    #pragma unroll 4
    for (int e = 0; e < cnt; ++e)
      a += ew[seg + e] * Xf[(size_t)etok[seg + e] * 1024 + d];
  } else {
    const u16* Xb = (const u16*)X;
    #pragma unroll 4
    for (int e = 0; e < cnt; ++e)
      a += ew[seg + e] * bf2f(Xb[(size_t)etok[seg + e] * 1024 + d]);
  }
  a *= 1.0f / (wsum[bs] + 1e-8f);
  splitf(a, gihi[(size_t)bs * 1024 + d], gilo[(size_t)bs * 1024 + d]);
}

// ---------------- GRU elementwise -> S_new split ----------------
__global__ __launch_bounds__(256) void k_gru(const float* __restrict__ gx,
    const float* __restrict__ gh, const float* __restrict__ hsf,
    u16* __restrict__ snhi, u16* __restrict__ snlo)
{
  int gid = blockIdx.x * 256 + threadIdx.x;
  int r = gid >> 10, d = gid & 1023, s = r & 63;
  const float* gxr = gx + (size_t)r * 3072;
  const float* ghr = gh + (size_t)s * 3072;
  float rr = 1.0f / (1.0f + expf(-(gxr[d] + ghr[d])));
  float zz = 1.0f / (1.0f + expf(-(gxr[1024 + d] + ghr[1024 + d])));
  float nn = tanhf(gxr[2048 + d] + rr * ghr[2048 + d]);
  float hv = (1.0f - zz) * nn + zz * hsf[s * 1024 + d];
  splitf(hv, snhi[gid], snlo[gid]);
}

// ---------------- out[n,:] = sum_k w_k * svo[b,id_k,:] ----------------
__global__ __launch_bounds__(256) void k_out(const int* __restrict__ idxb,
    const float* __restrict__ wgtb, const float* __restrict__ svo,
    const int* __restrict__ flagp, void* __restrict__ out)
{
  const int f32m = *flagp;
  int n = blockIdx.x * 4 + (threadIdx.x >> 6);
  int lane = threadIdx.x & 63;
  int b = n >> 12;
  const float* svb = svo + (size_t)b * 64 * 1024;
  int id[8]; float w[8];
  #pragma unroll
  for (int k = 0; k < 8; ++k) { id[k] = idxb[n * 8 + k]; w[k] = wgtb[n * 8 + k]; }
  #pragma unroll
  for (int i = 0; i < 16; ++i) {
    int d = i * 64 + lane;
    float a = 0.f;
    #pragma unroll
    for (int k = 0; k < 8; ++k) a += w[k] * svb[(size_t)id[k] * 1024 + d];
    size_t idx = (size_t)n * 1024 + d;
    if (f32m) ((float*)out)[idx] = a;
    else      ((u16*)out)[idx] = f2bf(a);
  }
}

// ---------------- launch ----------------
extern "C" void kernel_launch(void* const* d_in, const int* in_sizes, int n_in,
                              void* d_out, int out_size, void* d_ws, size_t ws_size,
                              hipStream_t stream) {
  if (ws_size < WS_NEED) {
    hipMemsetAsync(d_out, 0, (size_t)out_size * 2, stream);
    return;
  }
  const void* x    = d_in[0];
  const void* sli  = d_in[1];
  const void* slsc = d_in[2];
  const void* w1   = d_in[3];
  const void* b1   = d_in[4];
  const void* w2   = d_in[5];
  const void* b2   = d_in[6];
  const void* wih  = d_in[7];
  const void* whh  = d_in[8];
  const void* bih  = d_in[9];
  const void* bhh  = d_in[10];
  const void* wv   = d_in[11];
  const void* bv   = d_in[12];
  const void* wo   = d_in[13];
  const void* bo   = d_in[14];
  const void* tau  = d_in[15];
  char* ws = (char*)d_ws;

  int*    flag    = (int*)(ws + OFF_FLAG);
  int*    fcnt    = (int*)(ws + OFF_FCNT);
  double* m64     = (double*)(ws + OFF_M);
  double* b1p64   = (double*)(ws + OFF_B1P64);
  float*  b1p32   = (float*)(ws + OFF_B1P32);
  float*  bihf    = (float*)(ws + OFF_BIHF);
  float*  bhhf    = (float*)(ws + OFF_BHHF);
  float*  bvf     = (float*)(ws + OFF_BVF);
  float*  bof     = (float*)(ws + OFF_BOF);
  int*    listcnt = (int*)(ws + OFF_LISTCNT);
  float*  wsum    = (float*)(ws + OFF_WSUM);
  int*    flags   = (int*)(ws + OFF_FLAGS);
  u16*    hshi    = (u16*)(ws + OFF_HSHI);
  u16*    hslo    = (u16*)(ws + OFF_HSLO);
  float*  hsf     = (float*)(ws + OFF_HSF);
  float*  gh      = (float*)(ws + OFF_GH);
  u16*    gihi    = (u16*)(ws + OFF_GIHI);
  u16*    gilo    = (u16*)(ws + OFF_GILO);
  float*  gx      = (float*)(ws + OFF_GX);
  u16*    snhi    = (u16*)(ws + OFF_SNHI);
  u16*    snlo    = (u16*)(ws + OFF_SNLO);
  u16*    svhi    = (u16*)(ws + OFF_SVHI);
  u16*    svlo    = (u16*)(ws + OFF_SVLO);
  float*  svo     = (float*)(ws + OFF_SVO);
  int*    idxb    = (int*)(ws + OFF_IDX);
  float*  wgtb    = (float*)(ws + OFF_WGT);
  float*  logits  = (float*)(ws + OFF_LOGITS);
  int*    etok    = (int*)(ws + OFF_ETOK);
  float*  ew      = (float*)(ws + OFF_EW);
  u16*    w1hi    = (u16*)(ws + OFF_W1HI);
  u16*    w1lo    = (u16*)(ws + OFF_W1LO);
  u16*    w2hi    = (u16*)(ws + OFF_W2HI);
  u16*    w2lo    = (u16*)(ws + OFF_W2LO);
  u16*    xhi     = (u16*)(ws + OFF_XHI);
  u16*    xlo     = (u16*)(ws + OFF_XLO);
  u16*    wihhi   = (u16*)(ws + OFF_WIHHI);
  u16*    wihlo   = (u16*)(ws + OFF_WIHLO);
  u16*    whhhi   = (u16*)(ws + OFF_WHHHI);
  u16*    whhlo   = (u16*)(ws + OFF_WHHLO);
  u16*    wvhi    = (u16*)(ws + OFF_WVHI);
  u16*    wvlo    = (u16*)(ws + OFF_WVLO);
  u16*    wohi    = (u16*)(ws + OFF_WOHI);
  u16*    wolo    = (u16*)(ws + OFF_WOLO);

  k_sniff<<<1, 64, 0, stream>>>((const u32*)w1, flag);
  k_init<<<64, 256, 0, stream>>>(sli, slsc, flag, bih, bhh, bv, bo, m64, fcnt,
                                 listcnt, wsum, hshi, hslo, hsf, bihf, bhhf, bvf, bof);
  k_b1p<<<2, 256, 0, stream>>>(w1, b1, flag, m64, b1p64, b1p32);
  k_cvt_x<<<16384, 256, 0, stream>>>(x, xhi, xlo, flag);
  k_cvt_w1w2<<<1056, 256, 0, stream>>>(w1, w1hi, w1lo, w2, w2hi, w2lo, flag);

  // router + fused logits partials (x splits dead afterwards)
  gemm_router_fused<<<dim3(128, 4), 256, 0, stream>>>(
      xhi, xlo, w1hi, w1lo, w2hi, w2lo, b1p32, logits);

  // late weight conversion (aliases the dead x-split region)
  k_cvt_late<<<8192, 256, 0, stream>>>(wih, wihhi, wihlo, whh, whhhi, whhlo,
                                       wv, wvhi, wvlo, wo, wohi, wolo, flag);

  k_topk<<<4096, 256, 0, stream>>>(logits, b2, tau, flag, idxb, wgtb, fcnt, flags);
  k_repair<<<1024, 256, 0, stream>>>(x, w1, w2, b2, tau, flag, b1p64, fcnt, flags,
                                     idxb, wgtb);
  k_lists<<<64, 256, 0, stream>>>(idxb, wgtb, listcnt, wsum, etok, ew);
  k_accum<<<1024, 256, 0, stream>>>(x, flag, listcnt, wsum, etok, ew, gihi, gilo);

  // gh = hs @ whh^T + bhh  (64 x 3072)
  gemm_bt<0><<<dim3(1, 24), 256, 0, stream>>>(
      hshi, hslo, whhhi, whhlo, 64, 3072, 1024, 1024, bhhf, gh, nullptr, nullptr);
  // gx = gi @ wih^T + bih  (256 x 3072)
  gemm_bt<0><<<dim3(2, 24), 256, 0, stream>>>(
      gihi, gilo, wihhi, wihlo, 256, 3072, 1024, 1024, bihf, gx, nullptr, nullptr);
  k_gru<<<1024, 256, 0, stream>>>(gx, gh, hsf, snhi, snlo);
  // sv = S_new @ wv^T + bv (256 x 1024) -> split
  gemm_bt<3><<<dim3(2, 8), 256, 0, stream>>>(
      snhi, snlo, wvhi, wvlo, 256, 1024, 1024, 1024, bvf, nullptr, svhi, svlo);
  // svo = sv @ wo^T + bo   (256 x 1024) -> f32
  gemm_bt<0><<<dim3(2, 8), 256, 0, stream>>>(
      svhi, svlo, wohi, wolo, 256, 1024, 1024, 1024, bof, svo, nullptr, nullptr);
  k_out<<<4096, 256, 0, stream>>>(idxb, wgtb, svo, flag, d_out);

  (void)in_sizes; (void)n_in; (void)out_size; (void)ws_size;
}